// Round 1
// baseline (4903.556 us; speedup 1.0000x reference)
//
#include <hip/hip_runtime.h>
#include <stdint.h>

typedef short short8 __attribute__((ext_vector_type(8)));
typedef float f32x4 __attribute__((ext_vector_type(4)));
typedef float f32x2 __attribute__((ext_vector_type(2)));

#define TSEQ   128
#define BATCH  64
#define DIM    512
#define HID    1024
#define G3     3072
#define MROWS  (TSEQ * BATCH)   // 8192
#define NB     128              // gru grid
#define HB     8                // hidden units per gru block

__device__ __forceinline__ unsigned short f2bf(float f) {
  union { float f; unsigned u; } v; v.f = f;
  unsigned u = v.u;
  return (unsigned short)((u + 0x7FFFu + ((u >> 16) & 1u)) >> 16);
}

__device__ __forceinline__ short8 pack8(f32x4 a, f32x4 b) {
  short8 r;
  r[0] = (short)f2bf(a.x); r[1] = (short)f2bf(a.y);
  r[2] = (short)f2bf(a.z); r[3] = (short)f2bf(a.w);
  r[4] = (short)f2bf(b.x); r[5] = (short)f2bf(b.y);
  r[6] = (short)f2bf(b.z); r[7] = (short)f2bf(b.w);
  return r;
}

__device__ __forceinline__ float sigm(float x) { return 1.0f / (1.0f + __expf(-x)); }
__device__ __forceinline__ float tanh_fast(float x) { return 2.0f / (1.0f + __expf(-2.0f * x)) - 1.0f; }

// ---------------- grid barrier (device-scope, graph-replay safe) ----------------
__device__ void gridbar(unsigned int* bar, unsigned int target, int nblocks) {
  __syncthreads();                 // drains this block's vmem before fence
  if (threadIdx.x == 0) {
    __threadfence();               // release: L2 writeback (cross-XCD visibility)
    unsigned prev = atomicAdd(&bar[0], 1u);
    if (prev == target * (unsigned)nblocks - 1u) {
      atomicExch(&bar[16], target);      // gen on separate cache line
    } else {
      while (atomicAdd(&bar[16], 0u) < target) { __builtin_amdgcn_s_sleep(1); }
    }
    __threadfence();               // acquire: invalidate stale L1/L2
  }
  __syncthreads();
}

// ---------------- prep: gather emb rows + convert Wih to bf16 ----------------
__global__ __launch_bounds__(256) void prep_kernel(
    const int* __restrict__ ids, const float* __restrict__ emb,
    const float* __restrict__ wih, unsigned short* __restrict__ X,
    unsigned short* __restrict__ Wb, unsigned int* bars, int nbar)
{
  int row = blockIdx.x;
  int tid = threadIdx.x;
  const float* srcp;
  unsigned short* dst;
  if (row < MROWS) {
    srcp = emb + (long)ids[row] * DIM;
    dst  = X + (long)row * DIM;
  } else {
    int wr = row - MROWS;
    srcp = wih + (long)wr * DIM;
    dst  = Wb + (long)wr * DIM;
  }
  int d = tid * 2;                         // 256 thr x 2 f32 = 512
  f32x2 v = *(const f32x2*)(srcp + d);
  unsigned pk = (unsigned)f2bf(v.x) | ((unsigned)f2bf(v.y) << 16);
  *(unsigned*)(dst + d) = pk;
  if (bars != nullptr && row == 0 && tid < nbar) bars[tid] = 0u;
}

// ---------------- xW GEMM: C[m][n] = sum_k X[m][k]*W[n][k] + bih[n] ----------------
#define BM 128
#define BN 128
#define BK 32

__global__ __launch_bounds__(256) void xw_gemm(
    const unsigned short* __restrict__ X,   // [8192][512] bf16
    const unsigned short* __restrict__ W,   // [3072][512] bf16
    const float* __restrict__ bih,          // [3072]
    float* __restrict__ out)                // [8192][3072] f32
{
  __shared__ unsigned short As[BM * BK];
  __shared__ unsigned short Bs[BN * BK];
  int tid = threadIdx.x;
  int w = tid >> 6, l = tid & 63;
  int m0 = blockIdx.y * BM;
  int n0 = blockIdx.x * BN;
  int wr = w >> 1, wc = w & 1;

  // staging: thread t covers (row r, 16B slot skq); swizzled slot s = ((r>>1)+kg)&3
  int sr = tid >> 2, skq = tid & 3;
  int sr2 = sr + 64;
  int sgk  = (skq - (sr  >> 1)) & 3;
  int sgk2 = (skq - (sr2 >> 1)) & 3;
  const unsigned short* gA0 = X + (long)(m0 + sr ) * DIM + sgk  * 8;
  const unsigned short* gA1 = X + (long)(m0 + sr2) * DIM + sgk2 * 8;
  const unsigned short* gB0 = W + (long)(n0 + sr ) * DIM + sgk  * 8;
  const unsigned short* gB1 = W + (long)(n0 + sr2) * DIM + sgk2 * 8;
  unsigned short* lA0 = As + sr  * BK + skq * 8;
  unsigned short* lA1 = As + sr2 * BK + skq * 8;
  unsigned short* lB0 = Bs + sr  * BK + skq * 8;
  unsigned short* lB1 = Bs + sr2 * BK + skq * 8;

  f32x4 acc[4][4];
  #pragma unroll
  for (int mt = 0; mt < 4; ++mt)
    #pragma unroll
    for (int nt = 0; nt < 4; ++nt) acc[mt][nt] = (f32x4){};

  short8 va0 = *(const short8*)(gA0);
  short8 va1 = *(const short8*)(gA1);
  short8 vb0 = *(const short8*)(gB0);
  short8 vb1 = *(const short8*)(gB1);

  int fr = l & 15, fk = l >> 4;
  for (int kt = 0; kt < DIM / BK; ++kt) {
    __syncthreads();
    *(short8*)lA0 = va0; *(short8*)lA1 = va1;
    *(short8*)lB0 = vb0; *(short8*)lB1 = vb1;
    __syncthreads();
    if (kt + 1 < DIM / BK) {
      int ko = (kt + 1) * BK;
      va0 = *(const short8*)(gA0 + ko);
      va1 = *(const short8*)(gA1 + ko);
      vb0 = *(const short8*)(gB0 + ko);
      vb1 = *(const short8*)(gB1 + ko);
    }
    short8 af[4], bf[4];
    #pragma unroll
    for (int mt = 0; mt < 4; ++mt) {
      int r = wr * 64 + mt * 16 + fr;
      int slot = ((r >> 1) + fk) & 3;
      af[mt] = *(const short8*)(As + r * BK + slot * 8);
    }
    #pragma unroll
    for (int nt = 0; nt < 4; ++nt) {
      int r = wc * 64 + nt * 16 + fr;
      int slot = ((r >> 1) + fk) & 3;
      bf[nt] = *(const short8*)(Bs + r * BK + slot * 8);
    }
    #pragma unroll
    for (int mt = 0; mt < 4; ++mt)
      #pragma unroll
      for (int nt = 0; nt < 4; ++nt)
        acc[mt][nt] = __builtin_amdgcn_mfma_f32_16x16x32_bf16(af[mt], bf[nt], acc[mt][nt], 0, 0, 0);
  }

  #pragma unroll
  for (int nt = 0; nt < 4; ++nt) {
    int n = n0 + wc * 64 + nt * 16 + fr;
    float bias = bih[n];
    #pragma unroll
    for (int mt = 0; mt < 4; ++mt) {
      int mbase = m0 + wr * 64 + mt * 16 + fk * 4;
      #pragma unroll
      for (int r = 0; r < 4; ++r)
        out[(long)(mbase + r) * G3 + n] = acc[mt][nt][r] + bias;
    }
  }
}

// ---------------- persistent masked GRU ----------------
// Transposed matvec: C[m][n] = sum_k Whh_rows[m][k] * h[n][k]
// m: 0-7 r-gate, 8-15 z-gate, 16-23 n-gate (local units), 24-31 pad. n = batch.
// Weights live in registers (A), h read from global bf16 (B), K split across 4 waves.
__global__ __launch_bounds__(256) void gru_kernel(
    const float* __restrict__ Whh, const float* __restrict__ bhh,
    const float* __restrict__ xw, const int* __restrict__ lengths,
    unsigned short* __restrict__ hbf,   // [2][BATCH][HID] bf16, double-buffered
    float* __restrict__ hf32,           // [BATCH][HID]
    unsigned int* __restrict__ bar, int T, int initzero)
{
  int tid = threadIdx.x;
  int w = tid >> 6, l = tid & 63;
  int fr = l & 15, fk = l >> 4;
  int U0 = blockIdx.x * HB;

  // ---- weight A-fragments -> registers (2 m-tiles x 8 ksteps x bf16x8) ----
  short8 areg[2][8];
  #pragma unroll
  for (int mt = 0; mt < 2; ++mt) {
    int m = mt * 16 + fr;
    int gate = m >> 3;
    int u = m & 7;
    #pragma unroll
    for (int ksl = 0; ksl < 8; ++ksl) {
      short8 v = {};
      if (gate < 3) {
        const float* p = Whh + (long)(gate * HID + U0 + u) * HID + (w * 256 + ksl * 32 + fk * 8);
        f32x4 v0 = *(const f32x4*)p;
        f32x4 v1 = *(const f32x4*)(p + 4);
        v = pack8(v0, v1);
      }
      areg[mt][ksl] = v;
    }
  }

  // ---- per-thread gate state: owns units (j0, j0+1) of batch gb ----
  int gb = tid & 63;
  int j0 = (tid >> 6) * 2;
  long hoff = (long)gb * HID + U0 + j0;
  float h0, h1;
  if (initzero) {
    h0 = h1 = 0.0f;
    *(unsigned*)(hbf + hoff) = 0u;            // buffer 0
  } else {
    h0 = hf32[hoff]; h1 = hf32[hoff + 1];
  }
  float br0 = bhh[U0 + j0],            br1 = bhh[U0 + j0 + 1];
  float bz0 = bhh[HID + U0 + j0],      bz1 = bhh[HID + U0 + j0 + 1];
  float bn0 = bhh[2 * HID + U0 + j0],  bn1 = bhh[2 * HID + U0 + j0 + 1];
  int len_b = lengths[gb];

  __shared__ float red[4][32][64];   // 32 KB: per-wave K-partials

  gridbar(bar, 1u, NB);

  for (int t = 0; t < T; ++t) {
    const float* xwp = xw + ((long)t * BATCH + gb) * G3 + U0 + j0;
    f32x2 xr = *(const f32x2*)(xwp);
    f32x2 xz = *(const f32x2*)(xwp + HID);
    f32x2 xn = *(const f32x2*)(xwp + 2 * HID);

    const unsigned short* hb = hbf + (long)(t & 1) * (BATCH * HID);
    f32x4 acc[2][4];
    #pragma unroll
    for (int mt = 0; mt < 2; ++mt)
      #pragma unroll
      for (int nt = 0; nt < 4; ++nt) acc[mt][nt] = (f32x4){};

    #pragma unroll 2
    for (int ksl = 0; ksl < 8; ++ksl) {
      int k = w * 256 + ksl * 32 + fk * 8;
      #pragma unroll
      for (int nt = 0; nt < 4; ++nt) {
        short8 bfrag = *(const short8*)(hb + (long)(nt * 16 + fr) * HID + k);
        acc[0][nt] = __builtin_amdgcn_mfma_f32_16x16x32_bf16(areg[0][ksl], bfrag, acc[0][nt], 0, 0, 0);
        acc[1][nt] = __builtin_amdgcn_mfma_f32_16x16x32_bf16(areg[1][ksl], bfrag, acc[1][nt], 0, 0, 0);
      }
    }

    #pragma unroll
    for (int mt = 0; mt < 2; ++mt)
      #pragma unroll
      for (int nt = 0; nt < 4; ++nt)
        #pragma unroll
        for (int r = 0; r < 4; ++r)
          red[w][mt * 16 + fk * 4 + r][nt * 16 + fr] = acc[mt][nt][r];
    __syncthreads();

    float hr0 = red[0][j0][gb] + red[1][j0][gb] + red[2][j0][gb] + red[3][j0][gb] + br0;
    float hr1 = red[0][j0+1][gb] + red[1][j0+1][gb] + red[2][j0+1][gb] + red[3][j0+1][gb] + br1;
    float hz0 = red[0][8+j0][gb] + red[1][8+j0][gb] + red[2][8+j0][gb] + red[3][8+j0][gb] + bz0;
    float hz1 = red[0][9+j0][gb] + red[1][9+j0][gb] + red[2][9+j0][gb] + red[3][9+j0][gb] + bz1;
    float hn0 = red[0][16+j0][gb] + red[1][16+j0][gb] + red[2][16+j0][gb] + red[3][16+j0][gb] + bn0;
    float hn1 = red[0][17+j0][gb] + red[1][17+j0][gb] + red[2][17+j0][gb] + red[3][17+j0][gb] + bn1;

    float r0 = sigm(xr.x + hr0), r1 = sigm(xr.y + hr1);
    float z0 = sigm(xz.x + hz0), z1 = sigm(xz.y + hz1);
    float n0 = tanh_fast(xn.x + r0 * hn0), n1 = tanh_fast(xn.y + r1 * hn1);
    float c0 = (1.0f - z0) * n0 + z0 * h0;
    float c1 = (1.0f - z1) * n1 + z1 * h1;
    if (t < len_b) { h0 = c0; h1 = c1; }

    unsigned short* hwp = hbf + (long)((t + 1) & 1) * (BATCH * HID) + hoff;
    *(unsigned*)hwp = (unsigned)f2bf(h0) | ((unsigned)f2bf(h1) << 16);

    gridbar(bar, (unsigned)(t + 2), NB);
  }

  hf32[hoff]     = h0;
  hf32[hoff + 1] = h1;
}

// ---------------- head: logits = tanh(h @ p1^T + b1) @ p2^T + b2 ----------------
__global__ __launch_bounds__(256) void head_kernel(
    const float* __restrict__ hf32, const float* __restrict__ p1W,
    const float* __restrict__ p1b, const float* __restrict__ p2W,
    const float* __restrict__ p2b, float* __restrict__ outp)
{
  int b = blockIdx.x;
  int tid = threadIdx.x;
  __shared__ float hrow[HID];
  __shared__ float red[4][64];
  __shared__ float s1[64];
  for (int d = tid; d < HID; d += 256) hrow[d] = hf32[(long)b * HID + d];
  __syncthreads();
  int j = tid & 63, q = tid >> 6;
  const float* wrow = p1W + (long)j * HID + q * 256;
  float s = 0.0f;
  for (int k = 0; k < 256; ++k) s += hrow[q * 256 + k] * wrow[k];
  red[q][j] = s;
  __syncthreads();
  if (tid < 64) {
    float v = red[0][tid] + red[1][tid] + red[2][tid] + red[3][tid] + p1b[tid];
    s1[tid] = tanh_fast(v);
  }
  __syncthreads();
  if (tid < 2) {
    float a = p2b[tid];
    for (int k = 0; k < 64; ++k) a += s1[k] * p2W[tid * 64 + k];
    outp[b * 2 + tid] = a;
  }
}

// ---------------- launch ----------------
extern "C" void kernel_launch(void* const* d_in, const int* in_sizes, int n_in,
                              void* d_out, int out_size, void* d_ws, size_t ws_size,
                              hipStream_t stream) {
  const int*   tgt_ids = (const int*)d_in[0];
  const int*   tgt_len = (const int*)d_in[1];
  const int*   src_ids = (const int*)d_in[2];
  const int*   src_len = (const int*)d_in[3];
  const float* emb  = (const float*)d_in[6];
  const float* sWih = (const float*)d_in[7];
  const float* sWhh = (const float*)d_in[8];
  const float* sbih = (const float*)d_in[9];
  const float* sbhh = (const float*)d_in[10];
  const float* tWih = (const float*)d_in[11];
  const float* tWhh = (const float*)d_in[12];
  const float* tbih = (const float*)d_in[13];
  const float* tbhh = (const float*)d_in[14];
  const float* p1W  = (const float*)d_in[19];
  const float* p1b  = (const float*)d_in[20];
  const float* p2W  = (const float*)d_in[21];
  const float* p2b  = (const float*)d_in[22];

  char* ws = (char*)d_ws;
  size_t off = 0;
  float* xw = (float*)(ws + off);             off += (size_t)MROWS * G3 * 4;     // 100.7 MB
  unsigned short* X  = (unsigned short*)(ws + off); off += (size_t)MROWS * DIM * 2; // 8.4 MB
  unsigned short* Wb = (unsigned short*)(ws + off); off += (size_t)G3 * DIM * 2;    // 3.1 MB
  unsigned short* hbf = (unsigned short*)(ws + off); off += 2ull * BATCH * HID * 2;
  float* hf32 = (float*)(ws + off);           off += (size_t)BATCH * HID * 4;
  unsigned int* bars = (unsigned int*)(ws + off); off += 256;
  if (ws_size < off) return;  // insufficient scratch; fail visibly via mismatch

  const int PREP_BLOCKS = MROWS + G3;  // 11264

  // src pipeline
  prep_kernel<<<PREP_BLOCKS, 256, 0, stream>>>(src_ids, emb, sWih, X, Wb, bars, 64);
  xw_gemm<<<dim3(G3 / BN, MROWS / BM), 256, 0, stream>>>(X, Wb, sbih, xw);
  gru_kernel<<<NB, 256, 0, stream>>>(sWhh, sbhh, xw, src_len, hbf, hf32, bars, TSEQ, 1);
  // tgt pipeline (h0 = src final hidden, left in hbf buf0 / hf32)
  prep_kernel<<<PREP_BLOCKS, 256, 0, stream>>>(tgt_ids, emb, tWih, X, Wb, nullptr, 0);
  xw_gemm<<<dim3(G3 / BN, MROWS / BM), 256, 0, stream>>>(X, Wb, tbih, xw);
  gru_kernel<<<NB, 256, 0, stream>>>(tWhh, tbhh, xw, tgt_len, hbf, hf32, bars + 32, TSEQ, 0);
  // head
  head_kernel<<<BATCH, 256, 0, stream>>>(hf32, p1W, p1b, p2W, p2b, (float*)d_out);
}